// Round 4
// baseline (267.906 us; speedup 1.0000x reference)
//
#include <hip/hip_runtime.h>
#include <stdint.h>

// CTC forward loss (blank=0, reduction='mean', raw logits as log-probs).
// Linear-probability domain in DOUBLE precision: double's 2^+-1022 range
// covers the measured inter-state spread (~2^-250) with huge margin, so a
// single wave-uniform pow2 renorm every 32 steps suffices -- no per-lane
// scale tracking, no merge logic on the critical path.
// One 64-lane wave per sample; lane l owns states 8l..8l+7 (512 states
// suffice: end = 2*target_len <= 510; deps only flow upward in s).
// Logits rows stream through an LDS ring via global_load_lds DMA.

constexpr int T_DIM = 1024;
constexpr int V_DIM = 1024;
constexpr int S_MAX = 256;
constexpr int RING  = 12;   // ring rows; counted waits hard-code 44/40

constexpr float INV_LN2 = 1.44269504088896340736f;
constexpr float LN2f    = 0.69314718055994530942f;

__device__ __forceinline__ float exp2_hw(float x) {
    float r; asm("v_exp_f32 %0, %1" : "=v"(r) : "v"(x)); return r;
}
__device__ __forceinline__ float log2_hw(float x) {
    float r; asm("v_log_f32 %0, %1" : "=v"(r) : "v"(x)); return r;
}
__device__ __forceinline__ void stage16(const float* g, float* lds) {
    __builtin_amdgcn_global_load_lds(
        (const __attribute__((address_space(1))) void*)(uintptr_t)g,
        (__attribute__((address_space(3))) void*)(uint32_t)(uintptr_t)lds,
        16, 0, 0);
}
__device__ __forceinline__ int imax(int a, int b) { return a > b ? a : b; }

__launch_bounds__(64, 1)
__global__ void ctc_alpha_f64(const float* __restrict__ logits,
                              const int* __restrict__ targets,
                              const int* __restrict__ tlen,
                              float* __restrict__ losses) {
    __shared__ float  ring[RING][V_DIM];   // 48 KB
    __shared__ double afin[512];           // 4 KB

    const int n = blockIdx.x;
    const int l = threadIdx.x;             // 0..63

    // odd states 8l+1,3,5,7 -> labels targets[4l+0..3]
    const int* tg = targets + n * S_MAX;
    const int c0 = tg[4*l+0], c1 = tg[4*l+1], c2 = tg[4*l+2], c3 = tg[4*l+3];
    const int pv = (l > 0) ? tg[4*l-1] : 0;
    const double am0 = (l > 0 && c0 != pv) ? 1.0 : 0.0;   // skip-allow masks
    const double am1 = (c1 != c0) ? 1.0 : 0.0;
    const double am2 = (c2 != c1) ? 1.0 : 0.0;
    const double am3 = (c3 != c2) ? 1.0 : 0.0;

    const float* gbase = logits + (size_t)n * T_DIM * V_DIM;

    // Drain the targets loads so the counted vmcnt waits are exact.
    asm volatile("s_waitcnt vmcnt(0)" ::: "memory");

    for (int r = 0; r < RING; ++r) {       // 48 DMA loads outstanding
        const float* g = gbase + r * V_DIM + l * 4;
        stage16(g,       &ring[r][0]);
        stage16(g + 256, &ring[r][256]);
        stage16(g + 512, &ring[r][512]);
        stage16(g + 768, &ring[r][768]);
    }

    asm volatile("s_waitcnt vmcnt(44)" ::: "memory");   // row 0 resident
    double A0=0,A1=0,A2=0,A3=0,A4=0,A5=0,A6=0,A7=0;
    if (l == 0) {
        A0 = (double)exp2_hw(ring[0][0]  * INV_LN2);
        A1 = (double)exp2_hw(ring[0][c0] * INV_LN2);
    }

    asm volatile("s_waitcnt vmcnt(40)" ::: "memory");   // row 1 resident
    double PB = (double)exp2_hw(ring[1][0]  * INV_LN2);
    double P0 = (double)exp2_hw(ring[1][c0] * INV_LN2);
    double P1 = (double)exp2_hw(ring[1][c1] * INV_LN2);
    double P2 = (double)exp2_hw(ring[1][c2] * INV_LN2);
    double P3 = (double)exp2_hw(ring[1][c3] * INV_LN2);

    int Ls = 0;               // wave-uniform log2 scale (int)
    double a7n = 0.0;         // alpha[8l-1] from lane l-1, pipelined 1 step
    int wr = 0, rd = 2;
    const float* gnext = gbase + RING * V_DIM;

    for (int t = 1; t <= T_DIM - RING; ++t) {
        {   // stage row t+RING-1 into slot (t-1)%RING
            const float* g = gnext + l * 4;
            stage16(g,       &ring[wr][0]);
            stage16(g + 256, &ring[wr][256]);
            stage16(g + 512, &ring[wr][512]);
            stage16(g + 768, &ring[wr][768]);
            gnext += V_DIM;
            if (++wr == RING) wr = 0;
        }
        asm volatile("s_waitcnt vmcnt(40)" ::: "memory");  // row t+1 resident
        const float* rp = ring[rd];
        if (++rd == RING) rd = 0;
        const float lb = rp[0], w0 = rp[c0], w1 = rp[c1], w2 = rp[c2], w3 = rp[c3];

        // alpha step t (probs PB..P3 are row t, computed last iteration)
        const double n7 = (l == 0) ? 0.0 : a7n;
        const double t0 = (A0 + n7) * PB;
        const double t1 = fma(am0, n7, A1 + A0) * P0;
        const double t2 = (A2 + A1) * PB;
        const double t3 = fma(am1, A1, A3 + A2) * P1;
        const double t4 = (A4 + A3) * PB;
        const double t5 = fma(am2, A3, A5 + A4) * P2;
        const double t6 = (A6 + A5) * PB;
        const double t7 = fma(am3, A5, A7 + A6) * P3;
        A0=t0; A1=t1; A2=t2; A3=t3; A4=t4; A5=t5; A6=t6; A7=t7;

        if ((t & 31) == 0) {   // wave-uniform renorm (cheap, exponent-only)
            int h = __double2hiint(A0);
            h = imax(h, __double2hiint(A1)); h = imax(h, __double2hiint(A2));
            h = imax(h, __double2hiint(A3)); h = imax(h, __double2hiint(A4));
            h = imax(h, __double2hiint(A5)); h = imax(h, __double2hiint(A6));
            h = imax(h, __double2hiint(A7));
            #pragma unroll
            for (int off = 1; off < 64; off <<= 1)
                h = imax(h, __shfl_xor(h, off));
            const int eu = ((h >> 20) & 0x7FF) - 1023;
            const double sc = __hiloint2double((1023 - eu) << 20, 0); // 2^-eu
            A0*=sc; A1*=sc; A2*=sc; A3*=sc; A4*=sc; A5*=sc; A6*=sc; A7*=sc;
            Ls += eu;
        }

        a7n = __shfl_up(A7, 1);   // issued now, consumed next iteration

        PB = (double)exp2_hw(lb * INV_LN2);   // row t+1 probs for next iter
        P0 = (double)exp2_hw(w0 * INV_LN2);
        P1 = (double)exp2_hw(w1 * INV_LN2);
        P2 = (double)exp2_hw(w2 * INV_LN2);
        P3 = (double)exp2_hw(w3 * INV_LN2);
    }

    asm volatile("s_waitcnt vmcnt(0)" ::: "memory");       // all rows resident
    for (int t = T_DIM - RING + 1; t < T_DIM; ++t) {
        const bool more = (t + 1 < T_DIM);
        float lb = 0, w0 = 0, w1 = 0, w2 = 0, w3 = 0;
        if (more) {
            const float* rp = ring[rd];
            if (++rd == RING) rd = 0;
            lb = rp[0]; w0 = rp[c0]; w1 = rp[c1]; w2 = rp[c2]; w3 = rp[c3];
        }
        const double n7 = (l == 0) ? 0.0 : a7n;
        const double t0 = (A0 + n7) * PB;
        const double t1 = fma(am0, n7, A1 + A0) * P0;
        const double t2 = (A2 + A1) * PB;
        const double t3 = fma(am1, A1, A3 + A2) * P1;
        const double t4 = (A4 + A3) * PB;
        const double t5 = fma(am2, A3, A5 + A4) * P2;
        const double t6 = (A6 + A5) * PB;
        const double t7 = fma(am3, A5, A7 + A6) * P3;
        A0=t0; A1=t1; A2=t2; A3=t3; A4=t4; A5=t5; A6=t6; A7=t7;

        a7n = __shfl_up(A7, 1);

        if (more) {
            PB = (double)exp2_hw(lb * INV_LN2);
            P0 = (double)exp2_hw(w0 * INV_LN2);
            P1 = (double)exp2_hw(w1 * INV_LN2);
            P2 = (double)exp2_hw(w2 * INV_LN2);
            P3 = (double)exp2_hw(w3 * INV_LN2);
        }
    }

    afin[8*l+0]=A0; afin[8*l+1]=A1; afin[8*l+2]=A2; afin[8*l+3]=A3;
    afin[8*l+4]=A4; afin[8*l+5]=A5; afin[8*l+6]=A6; afin[8*l+7]=A7;
    asm volatile("s_waitcnt lgkmcnt(0)" ::: "memory");  // single wave
    if (l == 0) {
        const int tl_ = tlen[n];
        const int e = 2 * tl_;                           // 256..510
        const double s = afin[e] + afin[e - 1];
        // log2 of a positive double via exponent split:
        const long long u = __double_as_longlong(s);
        const int e2 = (int)((u >> 52) & 0x7FF) - 1023;
        const double m = __longlong_as_double(
            (u & 0x000FFFFFFFFFFFFFLL) | 0x3FF0000000000000LL);  // [1,2)
        const float lf = log2_hw((float)m);
        const float ll = LN2f * ((float)(e2 + Ls) + lf);         // natural log
        losses[n] = -ll / (float)tl_;
    }
}

__global__ void reduce_mean_kernel(const float* __restrict__ losses,
                                   float* __restrict__ out, int N) {
    float v = 0.0f;
    for (int i = threadIdx.x; i < N; i += 64) v += losses[i];
    #pragma unroll
    for (int off = 32; off > 0; off >>= 1) v += __shfl_down(v, off);
    if (threadIdx.x == 0) out[0] = v / (float)N;
}

extern "C" void kernel_launch(void* const* d_in, const int* in_sizes, int n_in,
                              void* d_out, int out_size, void* d_ws, size_t ws_size,
                              hipStream_t stream) {
    const float* logits  = (const float*)d_in[0];
    const int*   targets = (const int*)d_in[1];
    // d_in[2] = input_lengths (all == T, unused)
    const int*   tlen    = (const int*)d_in[3];
    const int N = in_sizes[3];

    float* losses = (float*)d_ws;   // N floats of scratch

    ctc_alpha_f64<<<N, 64, 0, stream>>>(logits, targets, tlen, losses);
    reduce_mean_kernel<<<1, 64, 0, stream>>>(losses, (float*)d_out, N);
}

// Round 6
// 163.881 us; speedup vs baseline: 1.6348x; 1.6348x over previous
//
#include <hip/hip_runtime.h>
#include <stdint.h>

// CTC forward loss (blank=0, reduction='mean', raw logits as log-probs).
// Linear-probability domain in double precision (range 2^+-1022 swallows the
// inter-state spread, so one wave-uniform exponent renorm per 16 steps).
// One 64-lane wave per sample; lane l owns states 8l..8l+7 (512 states
// suffice: end = 2*target_len <= 510; deps only flow upward in s).
// Logits rows stream through a 16-slot LDS ring via global_load_lds DMA.
// Main loop unrolled x16: compile-time slot offsets, fixed gather address
// registers, gathers double-buffered, staging 13 rows ahead (vmcnt(52)).
// BUGFIX vs round 5: a7n (in-flight neighbor alpha, captured pre-renorm)
// must be rescaled by the same wave-uniform factor in the renorm block.

constexpr int T_DIM = 1024;
constexpr int V_DIM = 1024;
constexpr int S_MAX = 256;
constexpr int RING  = 16;

constexpr float INV_LN2 = 1.44269504088896340736f;
constexpr float LN2f    = 0.69314718055994530942f;

__device__ __forceinline__ float exp2_hw(float x) {
    float r; asm("v_exp_f32 %0, %1" : "=v"(r) : "v"(x)); return r;
}
__device__ __forceinline__ float log2_hw(float x) {
    float r; asm("v_log_f32 %0, %1" : "=v"(r) : "v"(x)); return r;
}
__device__ __forceinline__ void stage16(const float* g, float* lds) {
    __builtin_amdgcn_global_load_lds(
        (const __attribute__((address_space(1))) void*)(uintptr_t)g,
        (__attribute__((address_space(3))) void*)(uint32_t)(uintptr_t)lds,
        16, 0, 0);
}
__device__ __forceinline__ int imax(int a, int b) { return a > b ? a : b; }

__launch_bounds__(64, 1)
__global__ void ctc_alpha_f64(const float* __restrict__ logits,
                              const int* __restrict__ targets,
                              const int* __restrict__ tlen,
                              float* __restrict__ losses) {
    __shared__ float  ring[RING][V_DIM];   // 64 KB
    __shared__ double afin[512];           // 4 KB

    const int n = blockIdx.x;
    const int l = threadIdx.x;             // 0..63

    // odd states 8l+1,3,5,7 -> labels targets[4l+0..3]
    const int* tg = targets + n * S_MAX;
    const int c0 = tg[4*l+0], c1 = tg[4*l+1], c2 = tg[4*l+2], c3 = tg[4*l+3];
    const int pv = (l > 0) ? tg[4*l-1] : 0;
    const double am0 = (l > 0 && c0 != pv) ? 1.0 : 0.0;   // skip-allow masks
    const double am1 = (c1 != c0) ? 1.0 : 0.0;
    const double am2 = (c2 != c1) ? 1.0 : 0.0;
    const double am3 = (c3 != c2) ? 1.0 : 0.0;

    const float* gbase = logits + (size_t)n * T_DIM * V_DIM;

    // Drain the targets loads so counted vmcnt waits are exact.
    asm volatile("s_waitcnt vmcnt(0)" ::: "memory");

    #pragma unroll
    for (int r = 0; r < RING; ++r) {       // 64 DMA loads outstanding
        const float* g = gbase + r * V_DIM + l * 4;
        stage16(g,       &ring[r][0]);
        stage16(g + 256, &ring[r][256]);
        stage16(g + 512, &ring[r][512]);
        stage16(g + 768, &ring[r][768]);
    }

    asm volatile("s_waitcnt vmcnt(60)" ::: "memory");   // row 0 resident
    double A0=0,A1=0,A2=0,A3=0,A4=0,A5=0,A6=0,A7=0;
    if (l == 0) {
        A0 = (double)exp2_hw(ring[0][0]  * INV_LN2);
        A1 = (double)exp2_hw(ring[0][c0] * INV_LN2);
    }

    asm volatile("s_waitcnt vmcnt(56)" ::: "memory");   // row 1 resident
    double PB = (double)exp2_hw(ring[1][0]  * INV_LN2);  // P_cur = row 1
    double P0 = (double)exp2_hw(ring[1][c0] * INV_LN2);
    double P1 = (double)exp2_hw(ring[1][c1] * INV_LN2);
    double P2 = (double)exp2_hw(ring[1][c2] * INV_LN2);
    double P3 = (double)exp2_hw(ring[1][c3] * INV_LN2);

    asm volatile("s_waitcnt vmcnt(52)" ::: "memory");   // row 2 resident
    float rAlb = ring[2][0], rA0 = ring[2][c0], rA1 = ring[2][c1],
          rA2  = ring[2][c2], rA3 = ring[2][c3];        // row-2 raws
    float rBlb = 0, rB0 = 0, rB1 = 0, rB2 = 0, rB3 = 0;

    double a7n = 0.0;      // alpha[8l-1] from lane l-1 (pipelined 1 step)
    int Ls = 0;            // wave-uniform log2 scale
    const float* gstage = gbase + RING * V_DIM + l * 4;

#define ALPHA_STEP()                                                         \
    {                                                                        \
        const double n7 = (l == 0) ? 0.0 : a7n;                              \
        const double t0 = (A0 + n7) * PB;                                    \
        const double t1 = fma(am0, n7, A1 + A0) * P0;                        \
        const double t2 = (A2 + A1) * PB;                                    \
        const double t3 = fma(am1, A1, A3 + A2) * P1;                        \
        const double t4 = (A4 + A3) * PB;                                    \
        const double t5 = fma(am2, A3, A5 + A4) * P2;                        \
        const double t6 = (A6 + A5) * PB;                                    \
        const double t7 = fma(am3, A5, A7 + A6) * P3;                        \
        A0=t0; A1=t1; A2=t2; A3=t3; A4=t4; A5=t5; A6=t6; A7=t7;              \
    }

    // Substep J (time t = tb+J): stage row t+15 -> slot J; gather row t+2
    // raws from slot (J+3)&15 into FILL; alpha with P (row t); shfl A7;
    // exp2(CONS raws = row t+1, gathered last substep) -> P for t+1.
#define SUBSTEP(J, Clb,C0_,C1_,C2_,C3_, Flb,F0_,F1_,F2_,F3_)                 \
    {                                                                        \
        stage16(gstage,       &ring[J][0]);                                  \
        stage16(gstage + 256, &ring[J][256]);                                \
        stage16(gstage + 512, &ring[J][512]);                                \
        stage16(gstage + 768, &ring[J][768]);                                \
        gstage += V_DIM;                                                     \
        asm volatile("s_waitcnt vmcnt(52)" ::: "memory");                    \
        Flb = ring[(J+3)&15][0];                                             \
        F0_ = ring[(J+3)&15][c0];                                            \
        F1_ = ring[(J+3)&15][c1];                                            \
        F2_ = ring[(J+3)&15][c2];                                            \
        F3_ = ring[(J+3)&15][c3];                                            \
        ALPHA_STEP();                                                        \
        a7n = __shfl_up(A7, 1);                                              \
        PB = (double)exp2_hw(Clb * INV_LN2);                                 \
        P0 = (double)exp2_hw(C0_ * INV_LN2);                                 \
        P1 = (double)exp2_hw(C1_ * INV_LN2);                                 \
        P2 = (double)exp2_hw(C2_ * INV_LN2);                                 \
        P3 = (double)exp2_hw(C3_ * INV_LN2);                                 \
    }

    // Main: tb = 1,17,...,993 (63 bodies), covering t = 1..1008.
    for (int tb = 1; tb <= T_DIM - 2 * RING + 1; tb += RING) {
        SUBSTEP(0,  rAlb,rA0,rA1,rA2,rA3,  rBlb,rB0,rB1,rB2,rB3)
        SUBSTEP(1,  rBlb,rB0,rB1,rB2,rB3,  rAlb,rA0,rA1,rA2,rA3)
        SUBSTEP(2,  rAlb,rA0,rA1,rA2,rA3,  rBlb,rB0,rB1,rB2,rB3)
        SUBSTEP(3,  rBlb,rB0,rB1,rB2,rB3,  rAlb,rA0,rA1,rA2,rA3)
        SUBSTEP(4,  rAlb,rA0,rA1,rA2,rA3,  rBlb,rB0,rB1,rB2,rB3)
        SUBSTEP(5,  rBlb,rB0,rB1,rB2,rB3,  rAlb,rA0,rA1,rA2,rA3)
        SUBSTEP(6,  rAlb,rA0,rA1,rA2,rA3,  rBlb,rB0,rB1,rB2,rB3)
        SUBSTEP(7,  rBlb,rB0,rB1,rB2,rB3,  rAlb,rA0,rA1,rA2,rA3)
        SUBSTEP(8,  rAlb,rA0,rA1,rA2,rA3,  rBlb,rB0,rB1,rB2,rB3)
        SUBSTEP(9,  rBlb,rB0,rB1,rB2,rB3,  rAlb,rA0,rA1,rA2,rA3)
        SUBSTEP(10, rAlb,rA0,rA1,rA2,rA3,  rBlb,rB0,rB1,rB2,rB3)
        SUBSTEP(11, rBlb,rB0,rB1,rB2,rB3,  rAlb,rA0,rA1,rA2,rA3)
        SUBSTEP(12, rAlb,rA0,rA1,rA2,rA3,  rBlb,rB0,rB1,rB2,rB3)
        SUBSTEP(13, rBlb,rB0,rB1,rB2,rB3,  rAlb,rA0,rA1,rA2,rA3)
        SUBSTEP(14, rAlb,rA0,rA1,rA2,rA3,  rBlb,rB0,rB1,rB2,rB3)
        SUBSTEP(15, rBlb,rB0,rB1,rB2,rB3,  rAlb,rA0,rA1,rA2,rA3)
        {   // wave-uniform exponent renorm (every 16 steps)
            int h = __double2hiint(A0);
            h = imax(h, __double2hiint(A1)); h = imax(h, __double2hiint(A2));
            h = imax(h, __double2hiint(A3)); h = imax(h, __double2hiint(A4));
            h = imax(h, __double2hiint(A5)); h = imax(h, __double2hiint(A6));
            h = imax(h, __double2hiint(A7));
            #pragma unroll
            for (int off = 1; off < 64; off <<= 1)
                h = imax(h, __shfl_xor(h, off));
            const int eu = ((h >> 20) & 0x7FF) - 1023;
            const double sc = __hiloint2double((1023 - eu) << 20, 0); // 2^-eu
            A0*=sc; A1*=sc; A2*=sc; A3*=sc; A4*=sc; A5*=sc; A6*=sc; A7*=sc;
            a7n *= sc;   // BUGFIX: keep in-flight neighbor at the same scale
            Ls += eu;
        }
    }

    // Tail: t = 1009..1023 (all rows already staged).
    asm volatile("s_waitcnt vmcnt(0)" ::: "memory");
    for (int t = T_DIM - RING + 1; t < T_DIM; ++t) {
        ALPHA_STEP();
        a7n = __shfl_up(A7, 1);
        if (t < T_DIM - 1) {
            PB = (double)exp2_hw(rAlb * INV_LN2);
            P0 = (double)exp2_hw(rA0  * INV_LN2);
            P1 = (double)exp2_hw(rA1  * INV_LN2);
            P2 = (double)exp2_hw(rA2  * INV_LN2);
            P3 = (double)exp2_hw(rA3  * INV_LN2);
            const int r = t + 2;
            if (r < T_DIM) {
                const float* rp = ring[r & (RING - 1)];
                rAlb = rp[0]; rA0 = rp[c0]; rA1 = rp[c1];
                rA2  = rp[c2]; rA3 = rp[c3];
            }
        }
    }

    afin[8*l+0]=A0; afin[8*l+1]=A1; afin[8*l+2]=A2; afin[8*l+3]=A3;
    afin[8*l+4]=A4; afin[8*l+5]=A5; afin[8*l+6]=A6; afin[8*l+7]=A7;
    asm volatile("s_waitcnt lgkmcnt(0)" ::: "memory");  // single wave
    if (l == 0) {
        const int tl_ = tlen[n];
        const int e = 2 * tl_;                           // 256..510
        const double s = afin[e] + afin[e - 1];
        const long long u = __double_as_longlong(s);
        const int e2 = (int)((u >> 52) & 0x7FF) - 1023;
        const double m = __longlong_as_double(
            (u & 0x000FFFFFFFFFFFFFLL) | 0x3FF0000000000000LL);  // [1,2)
        const float lf = log2_hw((float)m);
        const float ll = LN2f * ((float)(e2 + Ls) + lf);         // natural log
        losses[n] = -ll / (float)tl_;
    }
#undef SUBSTEP
#undef ALPHA_STEP
}

__global__ void reduce_mean_kernel(const float* __restrict__ losses,
                                   float* __restrict__ out, int N) {
    float v = 0.0f;
    for (int i = threadIdx.x; i < N; i += 64) v += losses[i];
    #pragma unroll
    for (int off = 32; off > 0; off >>= 1) v += __shfl_down(v, off);
    if (threadIdx.x == 0) out[0] = v / (float)N;
}

extern "C" void kernel_launch(void* const* d_in, const int* in_sizes, int n_in,
                              void* d_out, int out_size, void* d_ws, size_t ws_size,
                              hipStream_t stream) {
    const float* logits  = (const float*)d_in[0];
    const int*   targets = (const int*)d_in[1];
    // d_in[2] = input_lengths (all == T, unused)
    const int*   tlen    = (const int*)d_in[3];
    const int N = in_sizes[3];

    float* losses = (float*)d_ws;   // N floats of scratch

    ctc_alpha_f64<<<N, 64, 0, stream>>>(logits, targets, tlen, losses);
    reduce_mean_kernel<<<1, 64, 0, stream>>>(losses, (float*)d_out, N);
}